// Round 5
// baseline (667.066 us; speedup 1.0000x reference)
//
#include <hip/hip_runtime.h>
#include <math.h>

#define NLEVELS 16
#define LOG2_T 19
#define TSIZE (1u << LOG2_T)
#define TMASK (TSIZE - 1u)
#define NPTS 1048576
#define HALFPTS (NPTS / 2)

typedef float vfloat2 __attribute__((ext_vector_type(2)));
typedef float vfloat4 __attribute__((ext_vector_type(4)));

struct Res16 { float r[NLEVELS]; };

// Main kernel (unchanged from round 4 — measured at the divergent-gather floor:
// ~6 lane-requests per point-level avg * ~2.5 cy/request capacity*latency limit).
// 2D grid: blockIdx.y = level, blockIdx.x = point block; level phasing keeps the
// active 4 MiB table slice L2-resident per XCD.
__global__ __launch_bounds__(256) void HashGridEncoder_68925635166659_kernel(
    const float* __restrict__ x,
    const vfloat2* __restrict__ table,
    vfloat2* __restrict__ dst,
    const uint32_t mn, const uint32_t ml,   // store index = n*mn + l*ml
    Res16 res)
{
    const int l = blockIdx.y;
    const int t = blockIdx.x * blockDim.x + threadIdx.x;
    const int nA = t;
    const int nB = t + HALFPTS;

    const float r = res.r[l];
    const vfloat2* __restrict__ tl  = table + (uint32_t)l * TSIZE;
    const vfloat4* __restrict__ tl4 = (const vfloat4*)tl;   // aligned entry pairs

    const float pxA = x[3 * nA + 0];
    const float pyA = x[3 * nA + 1];
    const float pzA = x[3 * nA + 2];
    const float pxB = x[3 * nB + 0];
    const float pyB = x[3 * nB + 1];
    const float pzB = x[3 * nB + 2];

    // ---- point A: exact reference f32 ops (mul, floor, sub) ----
    const float sxA = pxA * r, syA = pyA * r, szA = pzA * r;
    const float fxA = floorf(sxA), fyA = floorf(syA), fzA = floorf(szA);
    const float wxA = sxA - fxA, wyA = syA - fyA, wzA = szA - fzA;
    const uint32_t ixA = (uint32_t)(int)fxA;
    const uint32_t iyA = (uint32_t)(int)fyA;
    const uint32_t izA = (uint32_t)(int)fzA;
    const uint32_t hxA1 = ixA + 1u;                   // P1 = 1
    const uint32_t hyA0 = iyA * 2654435761u;
    const uint32_t hyA1 = hyA0 + 2654435761u;
    const uint32_t hzA0 = izA * 805459861u;
    const uint32_t hzA1 = hzA0 + 805459861u;
    const uint32_t bA00 = (ixA ^ hyA0 ^ hzA0) & TMASK;
    const uint32_t bA01 = (ixA ^ hyA0 ^ hzA1) & TMASK;
    const uint32_t bA10 = (ixA ^ hyA1 ^ hzA0) & TMASK;
    const uint32_t bA11 = (ixA ^ hyA1 ^ hzA1) & TMASK;
    const uint32_t eA00 = (hxA1 ^ hyA0 ^ hzA0) & TMASK;  // dx=1 indices
    const uint32_t eA01 = (hxA1 ^ hyA0 ^ hzA1) & TMASK;
    const uint32_t eA10 = (hxA1 ^ hyA1 ^ hzA0) & TMASK;
    const uint32_t eA11 = (hxA1 ^ hyA1 ^ hzA1) & TMASK;

    // ---- point B ----
    const float sxB = pxB * r, syB = pyB * r, szB = pzB * r;
    const float fxB = floorf(sxB), fyB = floorf(syB), fzB = floorf(szB);
    const float wxB = sxB - fxB, wyB = syB - fyB, wzB = szB - fzB;
    const uint32_t ixB = (uint32_t)(int)fxB;
    const uint32_t iyB = (uint32_t)(int)fyB;
    const uint32_t izB = (uint32_t)(int)fzB;
    const uint32_t hxB1 = ixB + 1u;
    const uint32_t hyB0 = iyB * 2654435761u;
    const uint32_t hyB1 = hyB0 + 2654435761u;
    const uint32_t hzB0 = izB * 805459861u;
    const uint32_t hzB1 = hzB0 + 805459861u;
    const uint32_t bB00 = (ixB ^ hyB0 ^ hzB0) & TMASK;
    const uint32_t bB01 = (ixB ^ hyB0 ^ hzB1) & TMASK;
    const uint32_t bB10 = (ixB ^ hyB1 ^ hzB0) & TMASK;
    const uint32_t bB11 = (ixB ^ hyB1 ^ hzB1) & TMASK;
    const uint32_t eB00 = (hxB1 ^ hyB0 ^ hzB0) & TMASK;
    const uint32_t eB01 = (hxB1 ^ hyB0 ^ hzB1) & TMASK;
    const uint32_t eB10 = (hxB1 ^ hyB1 ^ hzB0) & TMASK;
    const uint32_t eB11 = (hxB1 ^ hyB1 ^ hzB1) & TMASK;

    // ---- masked dx=1 gathers FIRST (predicate depends only on ix) ----
    vfloat2 cA100, cA101, cA110, cA111;
    vfloat2 cB100, cB101, cB110, cB111;
    const uint32_t oddA = ixA & 1u;
    const uint32_t oddB = ixB & 1u;
    if (oddA) {
        cA100 = tl[eA00];
        cA101 = tl[eA01];
        cA110 = tl[eA10];
        cA111 = tl[eA11];
    }
    if (oddB) {
        cB100 = tl[eB00];
        cB101 = tl[eB01];
        cB110 = tl[eB10];
        cB111 = tl[eB11];
    }

    // ---- 8 quad loads, independent, same latency round ----
    const vfloat4 qA00 = tl4[bA00 >> 1];
    const vfloat4 qA01 = tl4[bA01 >> 1];
    const vfloat4 qA10 = tl4[bA10 >> 1];
    const vfloat4 qA11 = tl4[bA11 >> 1];
    const vfloat4 qB00 = tl4[bB00 >> 1];
    const vfloat4 qB01 = tl4[bB01 >> 1];
    const vfloat4 qB10 = tl4[bB10 >> 1];
    const vfloat4 qB11 = tl4[bB11 >> 1];

    // dx=0 corners = quad half addressed by b (select by stored-index bit0).
    const vfloat2 cA000 = (bA00 & 1u) ? vfloat2{qA00.z, qA00.w} : vfloat2{qA00.x, qA00.y};
    const vfloat2 cA001 = (bA01 & 1u) ? vfloat2{qA01.z, qA01.w} : vfloat2{qA01.x, qA01.y};
    const vfloat2 cA010 = (bA10 & 1u) ? vfloat2{qA10.z, qA10.w} : vfloat2{qA10.x, qA10.y};
    const vfloat2 cA011 = (bA11 & 1u) ? vfloat2{qA11.z, qA11.w} : vfloat2{qA11.x, qA11.y};
    const vfloat2 cB000 = (bB00 & 1u) ? vfloat2{qB00.z, qB00.w} : vfloat2{qB00.x, qB00.y};
    const vfloat2 cB001 = (bB01 & 1u) ? vfloat2{qB01.z, qB01.w} : vfloat2{qB01.x, qB01.y};
    const vfloat2 cB010 = (bB10 & 1u) ? vfloat2{qB10.z, qB10.w} : vfloat2{qB10.x, qB10.y};
    const vfloat2 cB011 = (bB11 & 1u) ? vfloat2{qB11.z, qB11.w} : vfloat2{qB11.x, qB11.y};

    // dx=1 corners for even-ix lanes = the OTHER quad half.
    if (!oddA) {
        cA100 = (bA00 & 1u) ? vfloat2{qA00.x, qA00.y} : vfloat2{qA00.z, qA00.w};
        cA101 = (bA01 & 1u) ? vfloat2{qA01.x, qA01.y} : vfloat2{qA01.z, qA01.w};
        cA110 = (bA10 & 1u) ? vfloat2{qA10.x, qA10.y} : vfloat2{qA10.z, qA10.w};
        cA111 = (bA11 & 1u) ? vfloat2{qA11.x, qA11.y} : vfloat2{qA11.z, qA11.w};
    }
    if (!oddB) {
        cB100 = (bB00 & 1u) ? vfloat2{qB00.x, qB00.y} : vfloat2{qB00.z, qB00.w};
        cB101 = (bB01 & 1u) ? vfloat2{qB01.x, qB01.y} : vfloat2{qB01.z, qB01.w};
        cB110 = (bB10 & 1u) ? vfloat2{qB10.x, qB10.y} : vfloat2{qB10.z, qB10.w};
        cB111 = (bB11 & 1u) ? vfloat2{qB11.x, qB11.y} : vfloat2{qB11.z, qB11.w};
    }

    // ---- weighted accumulation, same corner order as reference ----
    {
        const float wx0 = 1.0f - wxA, wy0 = 1.0f - wyA, wz0 = 1.0f - wzA;
        float f0 = 0.0f, f1 = 0.0f, w;
        w = (wx0 * wy0) * wz0; f0 += cA000.x * w; f1 += cA000.y * w;
        w = (wx0 * wy0) * wzA; f0 += cA001.x * w; f1 += cA001.y * w;
        w = (wx0 * wyA) * wz0; f0 += cA010.x * w; f1 += cA010.y * w;
        w = (wx0 * wyA) * wzA; f0 += cA011.x * w; f1 += cA011.y * w;
        w = (wxA * wy0) * wz0; f0 += cA100.x * w; f1 += cA100.y * w;
        w = (wxA * wy0) * wzA; f0 += cA101.x * w; f1 += cA101.y * w;
        w = (wxA * wyA) * wz0; f0 += cA110.x * w; f1 += cA110.y * w;
        w = (wxA * wyA) * wzA; f0 += cA111.x * w; f1 += cA111.y * w;
        vfloat2 v; v.x = f0; v.y = f1;
        __builtin_nontemporal_store(v, dst + (uint32_t)nA * mn + (uint32_t)l * ml);
    }
    {
        const float wx0 = 1.0f - wxB, wy0 = 1.0f - wyB, wz0 = 1.0f - wzB;
        float f0 = 0.0f, f1 = 0.0f, w;
        w = (wx0 * wy0) * wz0; f0 += cB000.x * w; f1 += cB000.y * w;
        w = (wx0 * wy0) * wzB; f0 += cB001.x * w; f1 += cB001.y * w;
        w = (wx0 * wyB) * wz0; f0 += cB010.x * w; f1 += cB010.y * w;
        w = (wx0 * wyB) * wzB; f0 += cB011.x * w; f1 += cB011.y * w;
        w = (wxB * wy0) * wz0; f0 += cB100.x * w; f1 += cB100.y * w;
        w = (wxB * wy0) * wzB; f0 += cB101.x * w; f1 += cB101.y * w;
        w = (wxB * wyB) * wz0; f0 += cB110.x * w; f1 += cB110.y * w;
        w = (wxB * wyB) * wzB; f0 += cB111.x * w; f1 += cB111.y * w;
        vfloat2 v; v.x = f0; v.y = f1;
        __builtin_nontemporal_store(v, dst + (uint32_t)nB * mn + (uint32_t)l * ml);
    }
}

// Transpose ws[16][NPTS] -> out[NPTS][16].
// Round-5: 512-point tiles (64 KB in + 64 KB out per block, 2048 blocks), plain
// cacheable loads (ws may be L3-resident -> allow L2 allocation; main kernel is
// done so no pollution concern), nontemporal stores.
// LDS: row stride 514 vfloat2 = 4112 B (word-stride 1028): b128 tile writes are
// contiguous per wave (conflict-free, 16 B-aligned since 4112 % 16 == 0);
// transposed b64 reads hit banks (8c + 2p) % 32 -> exactly 2-way (free).
__global__ __launch_bounds__(256) void HashGridEncoder_68925635166659_transpose(
    const vfloat2* __restrict__ ws,
    vfloat4* __restrict__ out4)
{
    __shared__ vfloat2 tile[NLEVELS][514];   // 65,792 B
    const int t  = threadIdx.x;
    const int p0 = blockIdx.x * 512;

    const vfloat4* __restrict__ ws4 = (const vfloat4*)ws;
    #pragma unroll
    for (int k = 0; k < 16; ++k) {
        const int lin = k * 256 + t;        // 0..4095 over [16][256] vfloat4
        const int row = lin >> 8;
        const int col = lin & 255;
        const vfloat4 v = ws4[(size_t)row * (NPTS / 2) + (p0 >> 1) + col];
        *(vfloat4*)&tile[row][2 * col] = v;
    }
    __syncthreads();
    #pragma unroll
    for (int k = 0; k < 16; ++k) {
        const int lin = k * 256 + t;        // 0..4095 over [512 pts][8 chunks]
        const int p = lin >> 3;
        const int c = lin & 7;
        const vfloat2 a = tile[2 * c][p];
        const vfloat2 b = tile[2 * c + 1][p];
        vfloat4 v; v.x = a.x; v.y = a.y; v.z = b.x; v.w = b.y;
        __builtin_nontemporal_store(v, out4 + (size_t)(p0 + p) * 8 + c);
    }
}

extern "C" void kernel_launch(void* const* d_in, const int* in_sizes, int n_in,
                              void* d_out, int out_size, void* d_ws, size_t ws_size,
                              hipStream_t stream) {
    const float*   x     = (const float*)d_in[0];
    const vfloat2* table = (const vfloat2*)d_in[1];
    vfloat2*       out   = (vfloat2*)d_out;

    // Exact numpy recipe in double: floor(16 * growth^l), growth = exp(ln(256)/15)
    Res16 res;
    const double growth = exp((log(4096.0) - log(16.0)) / 15.0);
    for (int l = 0; l < NLEVELS; ++l)
        res.r[l] = (float)floor(16.0 * pow(growth, (double)l));

    const dim3 block(256, 1, 1);
    const dim3 grid(HALFPTS / 256, NLEVELS, 1);   // 2048 x 16, 2 pts/thread

    const size_t ws_needed = (size_t)NLEVELS * NPTS * sizeof(vfloat2);  // 128 MiB
    if (ws_size >= ws_needed && d_ws != nullptr) {
        vfloat2* ws = (vfloat2*)d_ws;
        HashGridEncoder_68925635166659_kernel<<<grid, block, 0, stream>>>(
            x, table, ws, 1u, (uint32_t)NPTS, res);
        HashGridEncoder_68925635166659_transpose<<<dim3(NPTS / 512, 1, 1), block, 0, stream>>>(
            ws, (vfloat4*)out);
    } else {
        HashGridEncoder_68925635166659_kernel<<<grid, block, 0, stream>>>(
            x, table, out, (uint32_t)NLEVELS, 1u, res);
    }
}

// Round 7
// 632.952 us; speedup vs baseline: 1.0539x; 1.0539x over previous
//
#include <hip/hip_runtime.h>
#include <math.h>

#define NLEVELS 16
#define LOG2_T 19
#define TSIZE (1u << LOG2_T)
#define TMASK (TSIZE - 1u)
#define NPTS 1048576
#define HALFPTS (NPTS / 2)

typedef float vfloat2 __attribute__((ext_vector_type(2)));
typedef float vfloat4 __attribute__((ext_vector_type(4)));

struct Res16 { float r[NLEVELS]; };

// Main kernel (unchanged since round 4 — measured stable at 447 µs, the
// divergent-gather floor: ~6 lane-requests/point-level * ~2.5 cy/request
// TA issue-rate limit). 2D grid: blockIdx.y = level, blockIdx.x = point block;
// level phasing keeps the active 4 MiB table slice L2-resident per XCD.
__global__ __launch_bounds__(256) void HashGridEncoder_68925635166659_kernel(
    const float* __restrict__ x,
    const vfloat2* __restrict__ table,
    vfloat2* __restrict__ dst,
    const uint32_t mn, const uint32_t ml,   // store index = n*mn + l*ml
    Res16 res)
{
    const int l = blockIdx.y;
    const int t = blockIdx.x * blockDim.x + threadIdx.x;
    const int nA = t;
    const int nB = t + HALFPTS;

    const float r = res.r[l];
    const vfloat2* __restrict__ tl  = table + (uint32_t)l * TSIZE;
    const vfloat4* __restrict__ tl4 = (const vfloat4*)tl;   // aligned entry pairs

    const float pxA = x[3 * nA + 0];
    const float pyA = x[3 * nA + 1];
    const float pzA = x[3 * nA + 2];
    const float pxB = x[3 * nB + 0];
    const float pyB = x[3 * nB + 1];
    const float pzB = x[3 * nB + 2];

    // ---- point A: exact reference f32 ops (mul, floor, sub) ----
    const float sxA = pxA * r, syA = pyA * r, szA = pzA * r;
    const float fxA = floorf(sxA), fyA = floorf(syA), fzA = floorf(szA);
    const float wxA = sxA - fxA, wyA = syA - fyA, wzA = szA - fzA;
    const uint32_t ixA = (uint32_t)(int)fxA;
    const uint32_t iyA = (uint32_t)(int)fyA;
    const uint32_t izA = (uint32_t)(int)fzA;
    const uint32_t hxA1 = ixA + 1u;                   // P1 = 1
    const uint32_t hyA0 = iyA * 2654435761u;
    const uint32_t hyA1 = hyA0 + 2654435761u;
    const uint32_t hzA0 = izA * 805459861u;
    const uint32_t hzA1 = hzA0 + 805459861u;
    const uint32_t bA00 = (ixA ^ hyA0 ^ hzA0) & TMASK;
    const uint32_t bA01 = (ixA ^ hyA0 ^ hzA1) & TMASK;
    const uint32_t bA10 = (ixA ^ hyA1 ^ hzA0) & TMASK;
    const uint32_t bA11 = (ixA ^ hyA1 ^ hzA1) & TMASK;
    const uint32_t eA00 = (hxA1 ^ hyA0 ^ hzA0) & TMASK;  // dx=1 indices
    const uint32_t eA01 = (hxA1 ^ hyA0 ^ hzA1) & TMASK;
    const uint32_t eA10 = (hxA1 ^ hyA1 ^ hzA0) & TMASK;
    const uint32_t eA11 = (hxA1 ^ hyA1 ^ hzA1) & TMASK;

    // ---- point B ----
    const float sxB = pxB * r, syB = pyB * r, szB = pzB * r;
    const float fxB = floorf(sxB), fyB = floorf(syB), fzB = floorf(szB);
    const float wxB = sxB - fxB, wyB = syB - fyB, wzB = szB - fzB;
    const uint32_t ixB = (uint32_t)(int)fxB;
    const uint32_t iyB = (uint32_t)(int)fyB;
    const uint32_t izB = (uint32_t)(int)fzB;
    const uint32_t hxB1 = ixB + 1u;
    const uint32_t hyB0 = iyB * 2654435761u;
    const uint32_t hyB1 = hyB0 + 2654435761u;
    const uint32_t hzB0 = izB * 805459861u;
    const uint32_t hzB1 = hzB0 + 805459861u;
    const uint32_t bB00 = (ixB ^ hyB0 ^ hzB0) & TMASK;
    const uint32_t bB01 = (ixB ^ hyB0 ^ hzB1) & TMASK;
    const uint32_t bB10 = (ixB ^ hyB1 ^ hzB0) & TMASK;
    const uint32_t bB11 = (ixB ^ hyB1 ^ hzB1) & TMASK;
    const uint32_t eB00 = (hxB1 ^ hyB0 ^ hzB0) & TMASK;
    const uint32_t eB01 = (hxB1 ^ hyB0 ^ hzB1) & TMASK;
    const uint32_t eB10 = (hxB1 ^ hyB1 ^ hzB0) & TMASK;
    const uint32_t eB11 = (hxB1 ^ hyB1 ^ hzB1) & TMASK;

    // ---- masked dx=1 gathers FIRST (predicate depends only on ix) ----
    vfloat2 cA100, cA101, cA110, cA111;
    vfloat2 cB100, cB101, cB110, cB111;
    const uint32_t oddA = ixA & 1u;
    const uint32_t oddB = ixB & 1u;
    if (oddA) {
        cA100 = tl[eA00];
        cA101 = tl[eA01];
        cA110 = tl[eA10];
        cA111 = tl[eA11];
    }
    if (oddB) {
        cB100 = tl[eB00];
        cB101 = tl[eB01];
        cB110 = tl[eB10];
        cB111 = tl[eB11];
    }

    // ---- 8 quad loads, independent, same latency round ----
    const vfloat4 qA00 = tl4[bA00 >> 1];
    const vfloat4 qA01 = tl4[bA01 >> 1];
    const vfloat4 qA10 = tl4[bA10 >> 1];
    const vfloat4 qA11 = tl4[bA11 >> 1];
    const vfloat4 qB00 = tl4[bB00 >> 1];
    const vfloat4 qB01 = tl4[bB01 >> 1];
    const vfloat4 qB10 = tl4[bB10 >> 1];
    const vfloat4 qB11 = tl4[bB11 >> 1];

    // dx=0 corners = quad half addressed by b (select by stored-index bit0).
    const vfloat2 cA000 = (bA00 & 1u) ? vfloat2{qA00.z, qA00.w} : vfloat2{qA00.x, qA00.y};
    const vfloat2 cA001 = (bA01 & 1u) ? vfloat2{qA01.z, qA01.w} : vfloat2{qA01.x, qA01.y};
    const vfloat2 cA010 = (bA10 & 1u) ? vfloat2{qA10.z, qA10.w} : vfloat2{qA10.x, qA10.y};
    const vfloat2 cA011 = (bA11 & 1u) ? vfloat2{qA11.z, qA11.w} : vfloat2{qA11.x, qA11.y};
    const vfloat2 cB000 = (bB00 & 1u) ? vfloat2{qB00.z, qB00.w} : vfloat2{qB00.x, qB00.y};
    const vfloat2 cB001 = (bB01 & 1u) ? vfloat2{qB01.z, qB01.w} : vfloat2{qB01.x, qB01.y};
    const vfloat2 cB010 = (bB10 & 1u) ? vfloat2{qB10.z, qB10.w} : vfloat2{qB10.x, qB10.y};
    const vfloat2 cB011 = (bB11 & 1u) ? vfloat2{qB11.z, qB11.w} : vfloat2{qB11.x, qB11.y};

    // dx=1 corners for even-ix lanes = the OTHER quad half.
    if (!oddA) {
        cA100 = (bA00 & 1u) ? vfloat2{qA00.x, qA00.y} : vfloat2{qA00.z, qA00.w};
        cA101 = (bA01 & 1u) ? vfloat2{qA01.x, qA01.y} : vfloat2{qA01.z, qA01.w};
        cA110 = (bA10 & 1u) ? vfloat2{qA10.x, qA10.y} : vfloat2{qA10.z, qA10.w};
        cA111 = (bA11 & 1u) ? vfloat2{qA11.x, qA11.y} : vfloat2{qA11.z, qA11.w};
    }
    if (!oddB) {
        cB100 = (bB00 & 1u) ? vfloat2{qB00.x, qB00.y} : vfloat2{qB00.z, qB00.w};
        cB101 = (bB01 & 1u) ? vfloat2{qB01.x, qB01.y} : vfloat2{qB01.z, qB01.w};
        cB110 = (bB10 & 1u) ? vfloat2{qB10.x, qB10.y} : vfloat2{qB10.z, qB10.w};
        cB111 = (bB11 & 1u) ? vfloat2{qB11.x, qB11.y} : vfloat2{qB11.z, qB11.w};
    }

    // ---- weighted accumulation, same corner order as reference ----
    {
        const float wx0 = 1.0f - wxA, wy0 = 1.0f - wyA, wz0 = 1.0f - wzA;
        float f0 = 0.0f, f1 = 0.0f, w;
        w = (wx0 * wy0) * wz0; f0 += cA000.x * w; f1 += cA000.y * w;
        w = (wx0 * wy0) * wzA; f0 += cA001.x * w; f1 += cA001.y * w;
        w = (wx0 * wyA) * wz0; f0 += cA010.x * w; f1 += cA010.y * w;
        w = (wx0 * wyA) * wzA; f0 += cA011.x * w; f1 += cA011.y * w;
        w = (wxA * wy0) * wz0; f0 += cA100.x * w; f1 += cA100.y * w;
        w = (wxA * wy0) * wzA; f0 += cA101.x * w; f1 += cA101.y * w;
        w = (wxA * wyA) * wz0; f0 += cA110.x * w; f1 += cA110.y * w;
        w = (wxA * wyA) * wzA; f0 += cA111.x * w; f1 += cA111.y * w;
        vfloat2 v; v.x = f0; v.y = f1;
        __builtin_nontemporal_store(v, dst + (uint32_t)nA * mn + (uint32_t)l * ml);
    }
    {
        const float wx0 = 1.0f - wxB, wy0 = 1.0f - wyB, wz0 = 1.0f - wzB;
        float f0 = 0.0f, f1 = 0.0f, w;
        w = (wx0 * wy0) * wz0; f0 += cB000.x * w; f1 += cB000.y * w;
        w = (wx0 * wy0) * wzB; f0 += cB001.x * w; f1 += cB001.y * w;
        w = (wx0 * wyB) * wz0; f0 += cB010.x * w; f1 += cB010.y * w;
        w = (wx0 * wyB) * wzB; f0 += cB011.x * w; f1 += cB011.y * w;
        w = (wxB * wy0) * wz0; f0 += cB100.x * w; f1 += cB100.y * w;
        w = (wxB * wy0) * wzB; f0 += cB101.x * w; f1 += cB101.y * w;
        w = (wxB * wyB) * wz0; f0 += cB110.x * w; f1 += cB110.y * w;
        w = (wxB * wyB) * wzB; f0 += cB111.x * w; f1 += cB111.y * w;
        vfloat2 v; v.x = f0; v.y = f1;
        __builtin_nontemporal_store(v, dst + (uint32_t)nB * mn + (uint32_t)l * ml);
    }
}

// Transpose ws[16][NPTS] -> out[NPTS][16].
// Round-6: occupancy-first. 128-pt tiles -> 16.6 KB LDS -> 8 blocks/CU
// (thread-limited max, 32 waves/CU) vs r4's 4 and r5's 2. r3(launch-bound) ->
// r4(16 waves, 76us) -> r5(8 waves, 114us) showed TLP dominates for this
// streaming kernel. Nontemporal both sides (r4 policy). 8192 blocks.
// LDS row stride 130 vfloat2 = 1040 B (16 B-aligned): b128 tile writes are
// wave-contiguous (conflict-free); transposed b64 reads ~4-way (1.58x on a
// minor phase, acceptable).
__global__ __launch_bounds__(256) void HashGridEncoder_68925635166659_transpose(
    const vfloat2* __restrict__ ws,
    vfloat4* __restrict__ out4)
{
    __shared__ vfloat2 tile[NLEVELS][130];   // 16,640 B
    const int t  = threadIdx.x;
    const int p0 = blockIdx.x * 128;

    const vfloat4* __restrict__ ws4 = (const vfloat4*)ws;
    #pragma unroll
    for (int k = 0; k < 4; ++k) {
        const int lin = k * 256 + t;        // 0..1023 over [16][64] vfloat4
        const int row = lin >> 6;
        const int col = lin & 63;
        const vfloat4 v = __builtin_nontemporal_load(
            ws4 + (size_t)row * (NPTS / 2) + (p0 >> 1) + col);
        *(vfloat4*)&tile[row][2 * col] = v;   // wave-contiguous, conflict-free
    }
    __syncthreads();
    #pragma unroll
    for (int k = 0; k < 4; ++k) {
        const int lin = k * 256 + t;        // 0..1023 over [128 pts][8 chunks]
        const int p = lin >> 3;
        const int c = lin & 7;
        const vfloat2 a = tile[2 * c][p];
        const vfloat2 b = tile[2 * c + 1][p];
        vfloat4 v; v.x = a.x; v.y = a.y; v.z = b.x; v.w = b.y;
        __builtin_nontemporal_store(v, out4 + (size_t)(p0 + p) * 8 + c);  // wave-contiguous
    }
}

extern "C" void kernel_launch(void* const* d_in, const int* in_sizes, int n_in,
                              void* d_out, int out_size, void* d_ws, size_t ws_size,
                              hipStream_t stream) {
    const float*   x     = (const float*)d_in[0];
    const vfloat2* table = (const vfloat2*)d_in[1];
    vfloat2*       out   = (vfloat2*)d_out;

    // Exact numpy recipe in double: floor(16 * growth^l), growth = exp(ln(256)/15)
    Res16 res;
    const double growth = exp((log(4096.0) - log(16.0)) / 15.0);
    for (int l = 0; l < NLEVELS; ++l)
        res.r[l] = (float)floor(16.0 * pow(growth, (double)l));

    const dim3 block(256, 1, 1);
    const dim3 grid(HALFPTS / 256, NLEVELS, 1);   // 2048 x 16, 2 pts/thread

    const size_t ws_needed = (size_t)NLEVELS * NPTS * sizeof(vfloat2);  // 128 MiB
    if (ws_size >= ws_needed && d_ws != nullptr) {
        vfloat2* ws = (vfloat2*)d_ws;
        HashGridEncoder_68925635166659_kernel<<<grid, block, 0, stream>>>(
            x, table, ws, 1u, (uint32_t)NPTS, res);
        HashGridEncoder_68925635166659_transpose<<<dim3(NPTS / 128, 1, 1), block, 0, stream>>>(
            ws, (vfloat4*)out);
    } else {
        HashGridEncoder_68925635166659_kernel<<<grid, block, 0, stream>>>(
            x, table, out, (uint32_t)NLEVELS, 1u, res);
    }
}